// Round 4
// baseline (264.649 us; speedup 1.0000x reference)
//
#include <hip/hip_runtime.h>
#include <hip/hip_bf16.h>

typedef __attribute__((ext_vector_type(8))) short short8;
typedef __attribute__((ext_vector_type(4))) float float4v;

// Workspace layout (bytes):
//   xT   bf16 [16][34][34][256]                          : 9,469,952
//   Wg   bf16 [9][4][2][8][128][8] (s,pair,nt,qq,n,c8)   : 1,179,648
//   biasout f32 [256]                                    : 1,024
#define XT_ELEMS (16*34*34*256)
#define WG_ELEMS (9*4*2*8*128*8)
#define XT_BYTES (XT_ELEMS*2)
#define WG_BYTES (WG_ELEMS*2)

// ---------------------------------------------------------------------------
// Kernel 0: x f32 [16][256][32][32] -> xT bf16 [16][34][34][256].
// 512 blocks = (b, h). float4 reads, LDS transpose, bf16x2 writes.
// Blocks with h<2 also zero the pad ring. ~86 MB HBM => ~14 us floor.
// ---------------------------------------------------------------------------
__global__ __launch_bounds__(256) void k_transpose(const float* __restrict__ x,
                                                   __hip_bfloat16* __restrict__ xT) {
  __shared__ float tile[256 * 33];
  int blk = blockIdx.x;            // b*32 + h
  int h = blk & 31, b = blk >> 5;
  int tid = threadIdx.x;
  {
    int w4 = (tid & 7) * 4, c0 = tid >> 3;
#pragma unroll
    for (int j = 0; j < 8; ++j) {
      int ci = c0 + 32 * j;
      float4 v = *(const float4*)&x[((b * 256 + ci) * 32 + h) * 32 + w4];
      *(float4*)&tile[ci * 33 + w4] = v;
    }
  }
  __syncthreads();
  {
    int c2 = (tid & 127) * 2, wbase = (tid >> 7) * 16;
#pragma unroll
    for (int i = 0; i < 16; ++i) {
      int w = wbase + i;
      __hip_bfloat162 pk;
      pk.x = __float2bfloat16(tile[c2 * 33 + w]);
      pk.y = __float2bfloat16(tile[(c2 + 1) * 33 + w]);
      *(__hip_bfloat162*)&xT[((b * 34 + h + 1) * 34 + (w + 1)) * 256 + c2] = pk;
    }
  }
  if (h < 2) {
    uint4 z4 = {0u, 0u, 0u, 0u};
    int edge = h * 33;
    uint4* rowp = (uint4*)&xT[((b * 34 + edge) * 34) * 256];
    for (int i = tid; i < 1088; i += 256) rowp[i] = z4;
    for (int i = tid; i < 1024; i += 256) {
      int hh = 1 + (i >> 5);
      int c16 = (i & 31) * 8;
      *(uint4*)&xT[((b * 34 + hh) * 34 + edge) * 256 + c16] = z4;
    }
  }
}

// ---------------------------------------------------------------------------
// Kernel 1: build dense M_s = B2_s * B1_s, exact f32 in LDS. 145 blocks.
// ---------------------------------------------------------------------------
__global__ __launch_bounds__(256) void k_build_w(const float* __restrict__ tw1,
                                                 const float* __restrict__ tw2,
                                                 const float* __restrict__ bias,
                                                 __hip_bfloat16* __restrict__ Wg,
                                                 float* __restrict__ biasout) {
  __shared__ float mat[256 * 17];
  __shared__ __align__(16) float tws[2 * 255 * 4];
  int blk = blockIdx.x;
  int tid = threadIdx.x;
  if (blk == 144) {
    if (tid < 256) {
      float a = 0.f;
#pragma unroll
      for (int s = 0; s < 9; ++s) a += bias[s * 256 + tid];
      biasout[tid] = a * (1.f / 9.f);
    }
    return;
  }
  int sidx = blk >> 4;
  int colbase = (blk & 15) * 16;

  for (int i = tid; i < 255 * 4; i += 256) {
    tws[i]           = tw1[sidx * 255 * 4 + i];
    tws[255 * 4 + i] = tw2[sidx * 255 * 4 + i];
  }
  {
    int r = tid;
#pragma unroll
    for (int c = 0; c < 16; ++c) mat[r * 17 + c] = (r == colbase + c) ? 1.f : 0.f;
  }

  int c  = tid & 15;
  int pg = tid >> 4;
  for (int ph = 0; ph < 2; ++ph) {
    for (int si = 0; si < 8; ++si) {
      int lg = ph ? si : (7 - si);
      int st = 1 << lg;
      __syncthreads();
      float x0[8], x1[8], t0[8], t1[8], t2[8], t3[8];
#pragma unroll
      for (int i = 0; i < 8; ++i) {
        int qp = pg * 8 + i;
        int li = qp & (st - 1);
        int gi = qp >> lg;
        int p0 = (gi << (lg + 1)) | li;
        int p1 = p0 + st;
        float4 tv = *(const float4*)&tws[(ph * 255 + st - 1 + li) * 4];
        t0[i] = tv.x; t1[i] = tv.y; t2[i] = tv.z; t3[i] = tv.w;
        x0[i] = mat[p0 * 17 + c];
        x1[i] = mat[p1 * 17 + c];
      }
#pragma unroll
      for (int i = 0; i < 8; ++i) {
        int qp = pg * 8 + i;
        int li = qp & (st - 1);
        int gi = qp >> lg;
        int p0 = (gi << (lg + 1)) | li;
        int p1 = p0 + st;
        mat[p0 * 17 + c] = t0[i] * x0[i] + t1[i] * x1[i];
        mat[p1 * 17 + c] = t2[i] * x0[i] + t3[i] * x1[i];
      }
    }
  }
  __syncthreads();

  // Scatter in GEMM A-staging order: [s][pair][nt][qq][nl][c8], fold 1/9.
  for (int idx = tid; idx < 256 * 16; idx += 256) {
    int r = idx >> 4, cc = idx & 15;
    int cg = colbase + cc;
    int pr = cg >> 6, qq = (cg >> 3) & 7, c8 = cg & 7;
    int nt = r >> 7, nl = r & 127;
    int o = ((((sidx * 4 + pr) * 2 + nt) * 8 + qq) * 128 + nl) * 8 + c8;
    Wg[o] = __float2bfloat16(mat[r * 17 + cc] * (1.f / 9.f));
  }
}

// ---------------------------------------------------------------------------
// Kernel 2 (R3: 8-wave k-split): implicit-GEMM conv, K=64 per step, 36 steps.
// 256 blocks x 512 threads. Block tile 128n x 128pix (minimal LDS bytes/FLOP).
// 8 waves = (wk k-half) x (wm n-half) x (wn pix-half): 2 waves/SIMD so ds_read
// waits overlap MFMA issue across waves. Per wave/step: 4 A-reads + 4 B-reads
// + 16 MFMA. Partial accs combined via 2-round LDS reduction; each k-half
// stores half the output columns.
// ---------------------------------------------------------------------------
#define LDS_A_SZ 16384
#define LDS_B_SZ (8 * 204 * 16)

__global__ __launch_bounds__(512, 2) void k_gemm(const __hip_bfloat16* __restrict__ xT,
                                                 const __hip_bfloat16* __restrict__ Wg,
                                                 const float* __restrict__ biasout,
                                                 float* __restrict__ out) {
  __shared__ __align__(16) char lds[2 * LDS_A_SZ + LDS_B_SZ];
  const char* WgB = (const char*)Wg;
  const char* xTB = (const char*)xT;

  int blk = blockIdx.x;
  int nt = blk & 1;
  int pt = blk >> 1;
  int b  = pt >> 3;
  int h0 = (pt & 7) * 4;

  int tid  = threadIdx.x;
  int lane = tid & 63;
  int wave = tid >> 6;            // 0..7
  int wk = wave >> 2;             // k-half
  int wm = (wave >> 1) & 1;       // n-half
  int wn = wave & 1;              // pixel-half
  int q0 = lane >> 4;             // 0..3
  int q  = q0 + wk * 4;           // qq 0..7
  int l16 = lane & 15;

  float4v acc[4][4];
#pragma unroll
  for (int r = 0; r < 4; ++r)
#pragma unroll
    for (int j = 0; j < 4; ++j) acc[r][j] = (float4v){0.f, 0.f, 0.f, 0.f};

  // Step-invariant fragment addresses (B gets a wave-uniform per-step offset).
  int aoff[4];
#pragma unroll
  for (int r = 0; r < 4; ++r) aoff[r] = (q * 128 + wm * 64 + r * 16 + l16) * 16;
  int boff[4];
#pragma unroll
  for (int j = 0; j < 4; ++j) {
    int p = wn * 64 + j * 16 + l16;
    boff[j] = 2 * LDS_A_SZ + (q * 204 + (p >> 5) * 34 + (p & 31)) * 16;
  }

  auto stage_a = [&](int step, int buf) {
    int p = step / 9, s = step - p * 9;
    const char* g = WgB + (((s * 4 + p) * 2 + nt) * 16384);
#pragma unroll
    for (int i = 0; i < 2; ++i) {
      int slotbase = i * 512 + wave * 64;   // wave-uniform
      __builtin_amdgcn_global_load_lds(
          (const __attribute__((address_space(1))) void*)(g + (slotbase + lane) * 16),
          (__attribute__((address_space(3))) void*)(lds + buf * LDS_A_SZ + slotbase * 16),
          16, 0, 0);
    }
  };

  auto stage_b = [&](int p) {
#pragma unroll
    for (int i = 0; i < 4; ++i) {
      int slot = i * 512 + tid;             // 1632 slots = [qq][pos]
      if (slot < 1632) {
        int qq  = slot / 204;
        int pos = slot - qq * 204;
        int hh  = pos / 34;
        int ww  = pos - hh * 34;
        const char* g = xTB + (((b * 34 + h0 + hh) * 34 + ww) * 256 +
                               p * 64 + qq * 8) * 2;
        __builtin_amdgcn_global_load_lds(
            (const __attribute__((address_space(1))) void*)g,
            (__attribute__((address_space(3))) void*)(lds + 2 * LDS_A_SZ +
                                                     (i * 512 + wave * 64) * 16),
            16, 0, 0);
      }
    }
  };

  auto do_step = [&](int step) {
    int p = step / 9, s = step - p * 9;
    int si = s / 3, sj = s - si * 3;
    int soff = (si * 34 + sj) * 16;           // wave-uniform scalar
    int abase = (step & 1) * LDS_A_SZ;
    short8 af[4], bfr[4];
#pragma unroll
    for (int r = 0; r < 4; ++r) af[r] = *(const short8*)(lds + abase + aoff[r]);
#pragma unroll
    for (int j = 0; j < 4; ++j) bfr[j] = *(const short8*)(lds + boff[j] + soff);
#pragma unroll
    for (int r = 0; r < 4; ++r)
#pragma unroll
      for (int j = 0; j < 4; ++j)
        acc[r][j] = __builtin_amdgcn_mfma_f32_16x16x32_bf16(af[r], bfr[j], acc[r][j], 0, 0, 0);
  };

  stage_a(0, 0);
  stage_b(0);
  __syncthreads();
  for (int step = 0; step < 36; ++step) {
    int p = step / 9, s = step - p * 9;
    if (s == 8) {
      if (p < 3) stage_a(step + 1, (step + 1) & 1);
      do_step(step);
      __syncthreads();
      if (p < 3) { stage_b(p + 1); __syncthreads(); }
    } else {
      stage_a(step + 1, (step + 1) & 1);
      do_step(step);
      __syncthreads();
    }
  }

  // Reduce k-halves: round A (j=0,1) wk1->wk0; round B (j=2,3) wk0->wk1.
  {
    int pr = wm * 2 + wn;
    __syncthreads();
    if (wk == 1) {
#pragma unroll
      for (int r = 0; r < 4; ++r)
#pragma unroll
        for (int jj = 0; jj < 2; ++jj)
          *(float4v*)(lds + (((pr * 4 + r) * 2 + jj) * 64 + lane) * 16) = acc[r][jj];
    }
    __syncthreads();
    if (wk == 0) {
#pragma unroll
      for (int r = 0; r < 4; ++r)
#pragma unroll
        for (int jj = 0; jj < 2; ++jj)
          acc[r][jj] += *(const float4v*)(lds + (((pr * 4 + r) * 2 + jj) * 64 + lane) * 16);
    }
    __syncthreads();
    if (wk == 0) {
#pragma unroll
      for (int r = 0; r < 4; ++r)
#pragma unroll
        for (int jj = 0; jj < 2; ++jj)
          *(float4v*)(lds + (((pr * 4 + r) * 2 + jj) * 64 + lane) * 16) = acc[r][2 + jj];
    }
    __syncthreads();
    if (wk == 1) {
#pragma unroll
      for (int r = 0; r < 4; ++r)
#pragma unroll
        for (int jj = 0; jj < 2; ++jj)
          acc[r][2 + jj] += *(const float4v*)(lds + (((pr * 4 + r) * 2 + jj) * 64 + lane) * 16);
    }
  }

  // Store: wk0 stores j=0,1; wk1 stores j=2,3. D layout: col=l16, row=q0*4+reg.
  int nbase = nt * 128 + wm * 64;
#pragma unroll
  for (int jj = 0; jj < 2; ++jj) {
    int j = wk * 2 + jj;
    int pp = wn * 64 + j * 16 + l16;
    int hr = h0 + (pp >> 5), wc = pp & 31;
#pragma unroll
    for (int r = 0; r < 4; ++r) {
      float4v v = acc[r][j];
#pragma unroll
      for (int reg = 0; reg < 4; ++reg) {
        int n = nbase + r * 16 + q0 * 4 + reg;
        out[((b * 256 + n) * 32 + hr) * 32 + wc] = v[reg] + biasout[n];
      }
    }
  }
}

// ---------------------------------------------------------------------------
extern "C" void kernel_launch(void* const* d_in, const int* in_sizes, int n_in,
                              void* d_out, int out_size, void* d_ws, size_t ws_size,
                              hipStream_t stream) {
  const float* x    = (const float*)d_in[0];
  const float* tw1  = (const float*)d_in[1];
  const float* tw2  = (const float*)d_in[2];
  const float* bias = (const float*)d_in[3];
  float* out = (float*)d_out;

  char* ws = (char*)d_ws;
  __hip_bfloat16* xT = (__hip_bfloat16*)ws;
  __hip_bfloat16* Wg = (__hip_bfloat16*)(ws + XT_BYTES);
  float* biasout     = (float*)(ws + XT_BYTES + WG_BYTES);

  k_transpose<<<512, 256, 0, stream>>>(x, xT);
  k_build_w<<<145, 256, 0, stream>>>(tw1, tw2, bias, Wg, biasout);
  k_gemm<<<256, 512, 0, stream>>>(xT, Wg, biasout, out);
}

// Round 6
// 123.399 us; speedup vs baseline: 2.1447x; 2.1447x over previous
//
#include <hip/hip_runtime.h>
#include <hip/hip_bf16.h>

typedef __attribute__((ext_vector_type(8))) short short8;
typedef __attribute__((ext_vector_type(4))) float float4v;

// Workspace layout (bytes):
//   xT   bf16 [16][34][34][256]                          : 9,469,952
//   Wg   bf16 [9][4][2][8][128][8] (s,pair,nt,qq,n,c8)   : 1,179,648
//   biasout f32 [256]                                    : 1,024
#define XT_ELEMS (16*34*34*256)
#define WG_ELEMS (9*4*2*8*128*8)
#define XT_BYTES (XT_ELEMS*2)
#define WG_BYTES (WG_ELEMS*2)

// ---------------------------------------------------------------------------
// Kernel 0: x f32 [16][256][32][32] -> xT bf16 [16][34][34][256].
// 512 blocks = (b, h). float4 reads, LDS transpose, bf16x2 writes.
// Blocks with h<2 also zero the pad ring. ~86 MB HBM => ~14 us floor.
// ---------------------------------------------------------------------------
__global__ __launch_bounds__(256) void k_transpose(const float* __restrict__ x,
                                                   __hip_bfloat16* __restrict__ xT) {
  __shared__ float tile[256 * 33];
  int blk = blockIdx.x;            // b*32 + h
  int h = blk & 31, b = blk >> 5;
  int tid = threadIdx.x;
  {
    int w4 = (tid & 7) * 4, c0 = tid >> 3;
#pragma unroll
    for (int j = 0; j < 8; ++j) {
      int ci = c0 + 32 * j;
      float4 v = *(const float4*)&x[((b * 256 + ci) * 32 + h) * 32 + w4];
      *(float4*)&tile[ci * 33 + w4] = v;
    }
  }
  __syncthreads();
  {
    int c2 = (tid & 127) * 2, wbase = (tid >> 7) * 16;
#pragma unroll
    for (int i = 0; i < 16; ++i) {
      int w = wbase + i;
      __hip_bfloat162 pk;
      pk.x = __float2bfloat16(tile[c2 * 33 + w]);
      pk.y = __float2bfloat16(tile[(c2 + 1) * 33 + w]);
      *(__hip_bfloat162*)&xT[((b * 34 + h + 1) * 34 + (w + 1)) * 256 + c2] = pk;
    }
  }
  if (h < 2) {
    uint4 z4 = {0u, 0u, 0u, 0u};
    int edge = h * 33;
    uint4* rowp = (uint4*)&xT[((b * 34 + edge) * 34) * 256];
    for (int i = tid; i < 1088; i += 256) rowp[i] = z4;
    for (int i = tid; i < 1024; i += 256) {
      int hh = 1 + (i >> 5);
      int c16 = (i & 31) * 8;
      *(uint4*)&xT[((b * 34 + hh) * 34 + edge) * 256 + c16] = z4;
    }
  }
}

// ---------------------------------------------------------------------------
// Kernel 1: build dense M_s = B2_s * B1_s, exact f32 in LDS. 145 blocks.
// ---------------------------------------------------------------------------
__global__ __launch_bounds__(256) void k_build_w(const float* __restrict__ tw1,
                                                 const float* __restrict__ tw2,
                                                 const float* __restrict__ bias,
                                                 __hip_bfloat16* __restrict__ Wg,
                                                 float* __restrict__ biasout) {
  __shared__ float mat[256 * 17];
  __shared__ __align__(16) float tws[2 * 255 * 4];
  int blk = blockIdx.x;
  int tid = threadIdx.x;
  if (blk == 144) {
    if (tid < 256) {
      float a = 0.f;
#pragma unroll
      for (int s = 0; s < 9; ++s) a += bias[s * 256 + tid];
      biasout[tid] = a * (1.f / 9.f);
    }
    return;
  }
  int sidx = blk >> 4;
  int colbase = (blk & 15) * 16;

  for (int i = tid; i < 255 * 4; i += 256) {
    tws[i]           = tw1[sidx * 255 * 4 + i];
    tws[255 * 4 + i] = tw2[sidx * 255 * 4 + i];
  }
  {
    int r = tid;
#pragma unroll
    for (int c = 0; c < 16; ++c) mat[r * 17 + c] = (r == colbase + c) ? 1.f : 0.f;
  }

  int c  = tid & 15;
  int pg = tid >> 4;
  for (int ph = 0; ph < 2; ++ph) {
    for (int si = 0; si < 8; ++si) {
      int lg = ph ? si : (7 - si);
      int st = 1 << lg;
      __syncthreads();
      float x0[8], x1[8], t0[8], t1[8], t2[8], t3[8];
#pragma unroll
      for (int i = 0; i < 8; ++i) {
        int qp = pg * 8 + i;
        int li = qp & (st - 1);
        int gi = qp >> lg;
        int p0 = (gi << (lg + 1)) | li;
        int p1 = p0 + st;
        float4 tv = *(const float4*)&tws[(ph * 255 + st - 1 + li) * 4];
        t0[i] = tv.x; t1[i] = tv.y; t2[i] = tv.z; t3[i] = tv.w;
        x0[i] = mat[p0 * 17 + c];
        x1[i] = mat[p1 * 17 + c];
      }
#pragma unroll
      for (int i = 0; i < 8; ++i) {
        int qp = pg * 8 + i;
        int li = qp & (st - 1);
        int gi = qp >> lg;
        int p0 = (gi << (lg + 1)) | li;
        int p1 = p0 + st;
        mat[p0 * 17 + c] = t0[i] * x0[i] + t1[i] * x1[i];
        mat[p1 * 17 + c] = t2[i] * x0[i] + t3[i] * x1[i];
      }
    }
  }
  __syncthreads();

  // Scatter in GEMM A-staging order: [s][pair][nt][qq][nl][c8], fold 1/9.
  for (int idx = tid; idx < 256 * 16; idx += 256) {
    int r = idx >> 4, cc = idx & 15;
    int cg = colbase + cc;
    int pr = cg >> 6, qq = (cg >> 3) & 7, c8 = cg & 7;
    int nt = r >> 7, nl = r & 127;
    int o = ((((sidx * 4 + pr) * 2 + nt) * 8 + qq) * 128 + nl) * 8 + c8;
    Wg[o] = __float2bfloat16(mat[r * 17 + cc] * (1.f / 9.f));
  }
}

// ---------------------------------------------------------------------------
// Kernel 2 (R5 = R4 resubmit after infra flake): 8-wave k-split implicit-GEMM.
// K=64/step, 36 steps, 256 blocks x 512 threads, tile 128n x 128pix.
// All acc[][] indices compile-time constant (R3's dynamic index spilled acc
// to scratch -> 1.27 GB HBM writes, 182 us).
// ---------------------------------------------------------------------------
#define LDS_A_SZ 16384
#define LDS_B_SZ (8 * 204 * 16)

__global__ __launch_bounds__(512, 2) void k_gemm(const __hip_bfloat16* __restrict__ xT,
                                                 const __hip_bfloat16* __restrict__ Wg,
                                                 const float* __restrict__ biasout,
                                                 float* __restrict__ out) {
  __shared__ __align__(16) char lds[2 * LDS_A_SZ + LDS_B_SZ];
  const char* WgB = (const char*)Wg;
  const char* xTB = (const char*)xT;

  int blk = blockIdx.x;
  int nt = blk & 1;
  int pt = blk >> 1;
  int b  = pt >> 3;
  int h0 = (pt & 7) * 4;

  int tid  = threadIdx.x;
  int lane = tid & 63;
  int wave = tid >> 6;            // 0..7
  int wk = wave >> 2;             // k-half
  int wm = (wave >> 1) & 1;       // n-half
  int wn = wave & 1;              // pixel-half
  int q0 = lane >> 4;             // 0..3
  int q  = q0 + wk * 4;           // qq 0..7
  int l16 = lane & 15;

  float4v acc[4][4];
#pragma unroll
  for (int r = 0; r < 4; ++r)
#pragma unroll
    for (int j = 0; j < 4; ++j) acc[r][j] = (float4v){0.f, 0.f, 0.f, 0.f};

  int aoff[4];
#pragma unroll
  for (int r = 0; r < 4; ++r) aoff[r] = (q * 128 + wm * 64 + r * 16 + l16) * 16;
  int boff[4];
#pragma unroll
  for (int j = 0; j < 4; ++j) {
    int p = wn * 64 + j * 16 + l16;
    boff[j] = 2 * LDS_A_SZ + (q * 204 + (p >> 5) * 34 + (p & 31)) * 16;
  }

  auto stage_a = [&](int step, int buf) {
    int p = step / 9, s = step - p * 9;
    const char* g = WgB + (((s * 4 + p) * 2 + nt) * 16384);
#pragma unroll
    for (int i = 0; i < 2; ++i) {
      int slotbase = i * 512 + wave * 64;   // wave-uniform
      __builtin_amdgcn_global_load_lds(
          (const __attribute__((address_space(1))) void*)(g + (slotbase + lane) * 16),
          (__attribute__((address_space(3))) void*)(lds + buf * LDS_A_SZ + slotbase * 16),
          16, 0, 0);
    }
  };

  auto stage_b = [&](int p) {
#pragma unroll
    for (int i = 0; i < 4; ++i) {
      int slot = i * 512 + tid;             // 1632 slots = [qq][pos]
      if (slot < 1632) {
        int qq  = slot / 204;
        int pos = slot - qq * 204;
        int hh  = pos / 34;
        int ww  = pos - hh * 34;
        const char* g = xTB + (((b * 34 + h0 + hh) * 34 + ww) * 256 +
                               p * 64 + qq * 8) * 2;
        __builtin_amdgcn_global_load_lds(
            (const __attribute__((address_space(1))) void*)g,
            (__attribute__((address_space(3))) void*)(lds + 2 * LDS_A_SZ +
                                                     (i * 512 + wave * 64) * 16),
            16, 0, 0);
      }
    }
  };

  auto do_step = [&](int step) {
    int p = step / 9, s = step - p * 9;
    int si = s / 3, sj = s - si * 3;
    int soff = (si * 34 + sj) * 16;           // wave-uniform scalar
    int abase = (step & 1) * LDS_A_SZ;
    short8 af[4], bfr[4];
#pragma unroll
    for (int r = 0; r < 4; ++r) af[r] = *(const short8*)(lds + abase + aoff[r]);
#pragma unroll
    for (int j = 0; j < 4; ++j) bfr[j] = *(const short8*)(lds + boff[j] + soff);
#pragma unroll
    for (int r = 0; r < 4; ++r)
#pragma unroll
      for (int j = 0; j < 4; ++j)
        acc[r][j] = __builtin_amdgcn_mfma_f32_16x16x32_bf16(af[r], bfr[j], acc[r][j], 0, 0, 0);
  };

  stage_a(0, 0);
  stage_b(0);
  __syncthreads();
  for (int step = 0; step < 36; ++step) {
    int p = step / 9, s = step - p * 9;
    if (s == 8) {
      if (p < 3) stage_a(step + 1, (step + 1) & 1);
      do_step(step);
      __syncthreads();
      if (p < 3) { stage_b(p + 1); __syncthreads(); }
    } else {
      stage_a(step + 1, (step + 1) & 1);
      do_step(step);
      __syncthreads();
    }
  }

  // Reduce k-halves: round A (j=0,1) wk1->wk0; round B (j=2,3) wk0->wk1.
  {
    int pr = wm * 2 + wn;
    __syncthreads();
    if (wk == 1) {
#pragma unroll
      for (int r = 0; r < 4; ++r)
#pragma unroll
        for (int jj = 0; jj < 2; ++jj)
          *(float4v*)(lds + (((pr * 4 + r) * 2 + jj) * 64 + lane) * 16) = acc[r][jj];
    }
    __syncthreads();
    if (wk == 0) {
#pragma unroll
      for (int r = 0; r < 4; ++r)
#pragma unroll
        for (int jj = 0; jj < 2; ++jj)
          acc[r][jj] += *(const float4v*)(lds + (((pr * 4 + r) * 2 + jj) * 64 + lane) * 16);
    }
    __syncthreads();
    if (wk == 0) {
#pragma unroll
      for (int r = 0; r < 4; ++r)
#pragma unroll
        for (int jj = 0; jj < 2; ++jj)
          *(float4v*)(lds + (((pr * 4 + r) * 2 + jj) * 64 + lane) * 16) = acc[r][2 + jj];
    }
    __syncthreads();
    if (wk == 1) {
#pragma unroll
      for (int r = 0; r < 4; ++r)
#pragma unroll
        for (int jj = 0; jj < 2; ++jj)
          acc[r][2 + jj] += *(const float4v*)(lds + (((pr * 4 + r) * 2 + jj) * 64 + lane) * 16);
    }
  }

  // Store with constant acc indices per branch: wk0 -> j=0,1 ; wk1 -> j=2,3.
  int nbase = nt * 128 + wm * 64;
  if (wk == 0) {
#pragma unroll
    for (int jj = 0; jj < 2; ++jj) {
      int pp = wn * 64 + jj * 16 + l16;
      int hr = h0 + (pp >> 5), wc = pp & 31;
#pragma unroll
      for (int r = 0; r < 4; ++r) {
        float4v v = acc[r][jj];
#pragma unroll
        for (int reg = 0; reg < 4; ++reg) {
          int n = nbase + r * 16 + q0 * 4 + reg;
          out[((b * 256 + n) * 32 + hr) * 32 + wc] = v[reg] + biasout[n];
        }
      }
    }
  } else {
#pragma unroll
    for (int jj = 0; jj < 2; ++jj) {
      int pp = wn * 64 + (2 + jj) * 16 + l16;
      int hr = h0 + (pp >> 5), wc = pp & 31;
#pragma unroll
      for (int r = 0; r < 4; ++r) {
        float4v v = acc[r][2 + jj];
#pragma unroll
        for (int reg = 0; reg < 4; ++reg) {
          int n = nbase + r * 16 + q0 * 4 + reg;
          out[((b * 256 + n) * 32 + hr) * 32 + wc] = v[reg] + biasout[n];
        }
      }
    }
  }
}

// ---------------------------------------------------------------------------
extern "C" void kernel_launch(void* const* d_in, const int* in_sizes, int n_in,
                              void* d_out, int out_size, void* d_ws, size_t ws_size,
                              hipStream_t stream) {
  const float* x    = (const float*)d_in[0];
  const float* tw1  = (const float*)d_in[1];
  const float* tw2  = (const float*)d_in[2];
  const float* bias = (const float*)d_in[3];
  float* out = (float*)d_out;

  char* ws = (char*)d_ws;
  __hip_bfloat16* xT = (__hip_bfloat16*)ws;
  __hip_bfloat16* Wg = (__hip_bfloat16*)(ws + XT_BYTES);
  float* biasout     = (float*)(ws + XT_BYTES + WG_BYTES);

  k_transpose<<<512, 256, 0, stream>>>(x, xT);
  k_build_w<<<145, 256, 0, stream>>>(tw1, tw2, bias, Wg, biasout);
  k_gemm<<<256, 512, 0, stream>>>(xT, Wg, biasout, out);
}

// Round 7
// 118.817 us; speedup vs baseline: 2.2274x; 1.0386x over previous
//
#include <hip/hip_runtime.h>
#include <hip/hip_bf16.h>

typedef __attribute__((ext_vector_type(8))) short short8;
typedef __attribute__((ext_vector_type(4))) float float4v;

// Workspace layout (bytes):
//   xT   bf16 [16][34][34][256]                          : 9,469,952
//   Wg   bf16 [9][4][2][8][128][8] (s,pair,nt,qq,n,c8)   : 1,179,648
//   biasout f32 [256]                                    : 1,024
#define XT_ELEMS (16*34*34*256)
#define WG_ELEMS (9*4*2*8*128*8)
#define XT_BYTES (XT_ELEMS*2)
#define WG_BYTES (WG_ELEMS*2)

// ---------------------------------------------------------------------------
// Kernel 0: x f32 [16][256][32][32] -> xT bf16 [16][34][34][256].
// 512 blocks = (b, h). float4 reads, LDS transpose, bf16x2 writes.
// Blocks with h<2 also zero the pad ring. ~86 MB HBM => ~13 us floor.
// ---------------------------------------------------------------------------
__global__ __launch_bounds__(256) void k_transpose(const float* __restrict__ x,
                                                   __hip_bfloat16* __restrict__ xT) {
  __shared__ float tile[256 * 33];
  int blk = blockIdx.x;            // b*32 + h
  int h = blk & 31, b = blk >> 5;
  int tid = threadIdx.x;
  {
    int w4 = (tid & 7) * 4, c0 = tid >> 3;
#pragma unroll
    for (int j = 0; j < 8; ++j) {
      int ci = c0 + 32 * j;
      float4 v = *(const float4*)&x[((b * 256 + ci) * 32 + h) * 32 + w4];
      *(float4*)&tile[ci * 33 + w4] = v;
    }
  }
  __syncthreads();
  {
    int c2 = (tid & 127) * 2, wbase = (tid >> 7) * 16;
#pragma unroll
    for (int i = 0; i < 16; ++i) {
      int w = wbase + i;
      __hip_bfloat162 pk;
      pk.x = __float2bfloat16(tile[c2 * 33 + w]);
      pk.y = __float2bfloat16(tile[(c2 + 1) * 33 + w]);
      *(__hip_bfloat162*)&xT[((b * 34 + h + 1) * 34 + (w + 1)) * 256 + c2] = pk;
    }
  }
  if (h < 2) {
    uint4 z4 = {0u, 0u, 0u, 0u};
    int edge = h * 33;
    uint4* rowp = (uint4*)&xT[((b * 34 + edge) * 34) * 256];
    for (int i = tid; i < 1088; i += 256) rowp[i] = z4;
    for (int i = tid; i < 1024; i += 256) {
      int hh = 1 + (i >> 5);
      int c16 = (i & 31) * 8;
      *(uint4*)&xT[((b * 34 + hh) * 34 + edge) * 256 + c16] = z4;
    }
  }
}

// ---------------------------------------------------------------------------
// Kernel 1: build dense M_s = B2_s * B1_s, exact f32 in LDS. 145 blocks.
// ---------------------------------------------------------------------------
__global__ __launch_bounds__(256) void k_build_w(const float* __restrict__ tw1,
                                                 const float* __restrict__ tw2,
                                                 const float* __restrict__ bias,
                                                 __hip_bfloat16* __restrict__ Wg,
                                                 float* __restrict__ biasout) {
  __shared__ float mat[256 * 17];
  __shared__ __align__(16) float tws[2 * 255 * 4];
  int blk = blockIdx.x;
  int tid = threadIdx.x;
  if (blk == 144) {
    if (tid < 256) {
      float a = 0.f;
#pragma unroll
      for (int s = 0; s < 9; ++s) a += bias[s * 256 + tid];
      biasout[tid] = a * (1.f / 9.f);
    }
    return;
  }
  int sidx = blk >> 4;
  int colbase = (blk & 15) * 16;

  for (int i = tid; i < 255 * 4; i += 256) {
    tws[i]           = tw1[sidx * 255 * 4 + i];
    tws[255 * 4 + i] = tw2[sidx * 255 * 4 + i];
  }
  {
    int r = tid;
#pragma unroll
    for (int c = 0; c < 16; ++c) mat[r * 17 + c] = (r == colbase + c) ? 1.f : 0.f;
  }

  int c  = tid & 15;
  int pg = tid >> 4;
  for (int ph = 0; ph < 2; ++ph) {
    for (int si = 0; si < 8; ++si) {
      int lg = ph ? si : (7 - si);
      int st = 1 << lg;
      __syncthreads();
      float x0[8], x1[8], t0[8], t1[8], t2[8], t3[8];
#pragma unroll
      for (int i = 0; i < 8; ++i) {
        int qp = pg * 8 + i;
        int li = qp & (st - 1);
        int gi = qp >> lg;
        int p0 = (gi << (lg + 1)) | li;
        int p1 = p0 + st;
        float4 tv = *(const float4*)&tws[(ph * 255 + st - 1 + li) * 4];
        t0[i] = tv.x; t1[i] = tv.y; t2[i] = tv.z; t3[i] = tv.w;
        x0[i] = mat[p0 * 17 + c];
        x1[i] = mat[p1 * 17 + c];
      }
#pragma unroll
      for (int i = 0; i < 8; ++i) {
        int qp = pg * 8 + i;
        int li = qp & (st - 1);
        int gi = qp >> lg;
        int p0 = (gi << (lg + 1)) | li;
        int p1 = p0 + st;
        mat[p0 * 17 + c] = t0[i] * x0[i] + t1[i] * x1[i];
        mat[p1 * 17 + c] = t2[i] * x0[i] + t3[i] * x1[i];
      }
    }
  }
  __syncthreads();

  // Scatter in GEMM A-staging order: [s][pair][nt][qq][nl][c8], fold 1/9.
  for (int idx = tid; idx < 256 * 16; idx += 256) {
    int r = idx >> 4, cc = idx & 15;
    int cg = colbase + cc;
    int pr = cg >> 6, qq = (cg >> 3) & 7, c8 = cg & 7;
    int nt = r >> 7, nl = r & 127;
    int o = ((((sidx * 4 + pr) * 2 + nt) * 8 + qq) * 128 + nl) * 8 + c8;
    Wg[o] = __float2bfloat16(mat[r * 17 + cc] * (1.f / 9.f));
  }
}

// ---------------------------------------------------------------------------
// Kernel 2 (R6: 2 blocks/CU): 8-wave k-split implicit-GEMM conv.
// Grid 512 = 16 b x 16 ptile(2 rows = 64 pix) x 2 nt; 512 threads.
// 2 blocks/CU co-resident (LDS 50.2 KB, launch_bounds(512,4)) so one block's
// barrier drains overlap the other block's compute (R2/R3/R6 showed the
// 1-block/CU structure is insensitive to loop shape -> residency-bound).
// Wave tile 64n x 32pix, acc[4][2]; K=64/step, 36 steps.
// ---------------------------------------------------------------------------
#define LDS_A_SZ 16384
#define LDS_B_SZ (8 * 136 * 16)

__global__ __launch_bounds__(512, 4) void k_gemm(const __hip_bfloat16* __restrict__ xT,
                                                 const __hip_bfloat16* __restrict__ Wg,
                                                 const float* __restrict__ biasout,
                                                 float* __restrict__ out) {
  __shared__ __align__(16) char lds[2 * LDS_A_SZ + LDS_B_SZ];
  const char* WgB = (const char*)Wg;
  const char* xTB = (const char*)xT;

  int blk = blockIdx.x;
  int nt = blk & 1;
  int pt = (blk >> 1) & 15;
  int b  = blk >> 5;
  int h0 = pt * 2;                 // output rows h0..h0+1 -> padded rows h0..h0+3

  int tid  = threadIdx.x;
  int lane = tid & 63;
  int wave = tid >> 6;            // 0..7
  int wk = wave >> 2;             // k-half
  int wm = (wave >> 1) & 1;       // n-half (64)
  int wn = wave & 1;              // pixel-half (32)
  int q0 = lane >> 4;             // 0..3
  int q  = q0 + wk * 4;           // qq 0..7
  int l16 = lane & 15;

  float4v acc[4][2];
#pragma unroll
  for (int r = 0; r < 4; ++r)
#pragma unroll
    for (int j = 0; j < 2; ++j) acc[r][j] = (float4v){0.f, 0.f, 0.f, 0.f};

  int aoff[4];
#pragma unroll
  for (int r = 0; r < 4; ++r) aoff[r] = (q * 128 + wm * 64 + r * 16 + l16) * 16;
  int boff[2];
#pragma unroll
  for (int j = 0; j < 2; ++j) {
    int p = wn * 32 + j * 16 + l16;           // 0..63
    boff[j] = 2 * LDS_A_SZ + (q * 136 + (p >> 5) * 34 + (p & 31)) * 16;
  }

  auto stage_a = [&](int step, int buf) {
    int p = step / 9, s = step - p * 9;
    const char* g = WgB + (((s * 4 + p) * 2 + nt) * 16384);
#pragma unroll
    for (int i = 0; i < 2; ++i) {
      int slotbase = i * 512 + wave * 64;   // wave-uniform
      __builtin_amdgcn_global_load_lds(
          (const __attribute__((address_space(1))) void*)(g + (slotbase + lane) * 16),
          (__attribute__((address_space(3))) void*)(lds + buf * LDS_A_SZ + slotbase * 16),
          16, 0, 0);
    }
  };

  auto stage_b = [&](int p) {
#pragma unroll
    for (int i = 0; i < 3; ++i) {
      int slot = i * 512 + tid;             // 1088 slots = [qq][pos], pos = hh*34+ww
      if (slot < 1088) {
        int qq  = slot / 136;
        int pos = slot - qq * 136;
        int hh  = pos / 34;
        int ww  = pos - hh * 34;
        const char* g = xTB + (((b * 34 + h0 + hh) * 34 + ww) * 256 +
                               p * 64 + qq * 8) * 2;
        __builtin_amdgcn_global_load_lds(
            (const __attribute__((address_space(1))) void*)g,
            (__attribute__((address_space(3))) void*)(lds + 2 * LDS_A_SZ +
                                                     (i * 512 + wave * 64) * 16),
            16, 0, 0);
      }
    }
  };

  auto do_step = [&](int step) {
    int p = step / 9, s = step - p * 9;
    int si = s / 3, sj = s - si * 3;
    int soff = (si * 34 + sj) * 16;           // wave-uniform scalar
    int abase = (step & 1) * LDS_A_SZ;
    short8 af[4], bfr[2];
#pragma unroll
    for (int r = 0; r < 4; ++r) af[r] = *(const short8*)(lds + abase + aoff[r]);
#pragma unroll
    for (int j = 0; j < 2; ++j) bfr[j] = *(const short8*)(lds + boff[j] + soff);
#pragma unroll
    for (int r = 0; r < 4; ++r)
#pragma unroll
      for (int j = 0; j < 2; ++j)
        acc[r][j] = __builtin_amdgcn_mfma_f32_16x16x32_bf16(af[r], bfr[j], acc[r][j], 0, 0, 0);
  };

  stage_a(0, 0);
  stage_b(0);
  __syncthreads();
  for (int step = 0; step < 36; ++step) {
    int p = step / 9, s = step - p * 9;
    if (s == 8) {
      if (p < 3) stage_a(step + 1, (step + 1) & 1);
      do_step(step);
      __syncthreads();
      if (p < 3) { stage_b(p + 1); __syncthreads(); }
    } else {
      stage_a(step + 1, (step + 1) & 1);
      do_step(step);
      __syncthreads();
    }
  }

  // Reduce k-halves (constant acc indices). Round 1: wk1 -> wk0 on j=0.
  // Round 2: wk0 -> wk1 on j=1. Reuse A-buffer LDS (16 KB).
  {
    int pr = wm * 2 + wn;
    __syncthreads();
    if (wk == 1) {
#pragma unroll
      for (int r = 0; r < 4; ++r)
        *(float4v*)(lds + ((pr * 4 + r) * 64 + lane) * 16) = acc[r][0];
    }
    __syncthreads();
    if (wk == 0) {
#pragma unroll
      for (int r = 0; r < 4; ++r)
        acc[r][0] += *(const float4v*)(lds + ((pr * 4 + r) * 64 + lane) * 16);
    }
    __syncthreads();
    if (wk == 0) {
#pragma unroll
      for (int r = 0; r < 4; ++r)
        *(float4v*)(lds + ((pr * 4 + r) * 64 + lane) * 16) = acc[r][1];
    }
    __syncthreads();
    if (wk == 1) {
#pragma unroll
      for (int r = 0; r < 4; ++r)
        acc[r][1] += *(const float4v*)(lds + ((pr * 4 + r) * 64 + lane) * 16);
    }
  }

  // Store: wk0 stores j=0 (pix quarter 0), wk1 stores j=1. Constant indices.
  int nbase = nt * 128 + wm * 64;
  if (wk == 0) {
    int pp = wn * 32 + l16;
    int hr = h0 + (pp >> 5), wc = pp & 31;
#pragma unroll
    for (int r = 0; r < 4; ++r) {
      float4v v = acc[r][0];
#pragma unroll
      for (int reg = 0; reg < 4; ++reg) {
        int n = nbase + r * 16 + q0 * 4 + reg;
        out[((b * 256 + n) * 32 + hr) * 32 + wc] = v[reg] + biasout[n];
      }
    }
  } else {
    int pp = wn * 32 + 16 + l16;
    int hr = h0 + (pp >> 5), wc = pp & 31;
#pragma unroll
    for (int r = 0; r < 4; ++r) {
      float4v v = acc[r][1];
#pragma unroll
      for (int reg = 0; reg < 4; ++reg) {
        int n = nbase + r * 16 + q0 * 4 + reg;
        out[((b * 256 + n) * 32 + hr) * 32 + wc] = v[reg] + biasout[n];
      }
    }
  }
}

// ---------------------------------------------------------------------------
extern "C" void kernel_launch(void* const* d_in, const int* in_sizes, int n_in,
                              void* d_out, int out_size, void* d_ws, size_t ws_size,
                              hipStream_t stream) {
  const float* x    = (const float*)d_in[0];
  const float* tw1  = (const float*)d_in[1];
  const float* tw2  = (const float*)d_in[2];
  const float* bias = (const float*)d_in[3];
  float* out = (float*)d_out;

  char* ws = (char*)d_ws;
  __hip_bfloat16* xT = (__hip_bfloat16*)ws;
  __hip_bfloat16* Wg = (__hip_bfloat16*)(ws + XT_BYTES);
  float* biasout     = (float*)(ws + XT_BYTES + WG_BYTES);

  k_transpose<<<512, 256, 0, stream>>>(x, xT);
  k_build_w<<<145, 256, 0, stream>>>(tw1, tw2, bias, Wg, biasout);
  k_gemm<<<512, 512, 0, stream>>>(xT, Wg, biasout, out);
}